// Round 5
// baseline (724.693 us; speedup 1.0000x reference)
//
#include <hip/hip_runtime.h>

typedef unsigned short u16;
typedef __bf16 bf16_t;
typedef bf16_t bf16x8 __attribute__((ext_vector_type(8)));
typedef float f32x4 __attribute__((ext_vector_type(4)));
typedef u16 u16x8 __attribute__((ext_vector_type(8)));

#define AS1 __attribute__((address_space(1)))
#define AS3 __attribute__((address_space(3)))

__device__ __forceinline__ u16 f2bf(float f) {
    union { float f; unsigned u; } v; v.f = f;
    unsigned r = v.u + 0x7FFFu + ((v.u >> 16) & 1u);
    return (u16)(r >> 16);
}
__device__ __forceinline__ float bf2f(u16 s) {
    union { unsigned u; float f; } v; v.u = ((unsigned)s) << 16;
    return v.f;
}

__device__ __forceinline__ void gload_lds16(const u16* g, u16* l) {
    __builtin_amdgcn_global_load_lds((AS1 const void*)g, (AS3 void*)l, 16, 0, 0);
}

// ---------------- big GEMM: C[M,N] = A[M,K] * B[N,K]^T, bf16 in, 128x128 tile ----
// m97 structure + G4 XOR swizzle + T1 bijective XCD-chunked block swizzle (m204).
template <bool OUT_BF16, bool GUARD>
__global__ __launch_bounds__(256) void gemm_bt(
    const u16* __restrict__ A, const u16* __restrict__ B, void* __restrict__ Cv,
    int K, int ldc, int Mreal, int Nreal)
{
    __shared__ u16 As[128 * 64];
    __shared__ u16 Bs[128 * 64];
    const int t = threadIdx.x;
    const int w = t >> 6, l = t & 63;

    const int nwg = gridDim.x * gridDim.y;
    const int lin = blockIdx.y * gridDim.x + blockIdx.x;
    const int xcd = lin & 7, loc = lin >> 3;
    const int q = nwg >> 3, r = nwg & 7;
    const int swz = (xcd < r ? xcd * (q + 1) : r * (q + 1) + (xcd - r) * q) + loc;
    const int bx = swz % gridDim.x, by = swz / gridDim.x;

    const int m0 = by * 128, n0 = bx * 128;
    const int wm = (w >> 1) * 64, wn = (w & 1) * 64;

    const int srow = w << 5;           // wave's 32-row staging base
    const int lrow = l >> 3, lc = l & 7;

    f32x4 acc[4][4] = {};

    for (int kt = 0; kt < K; kt += 64) {
#pragma unroll
        for (int i = 0; i < 4; ++i) {
            int row = srow + i * 8 + lrow;
            int gc = ((lc ^ (row & 7)) << 3);
            const u16* ga = A + (size_t)(m0 + row) * K + kt + gc;
            const u16* gb = B + (size_t)(n0 + row) * K + kt + gc;
            u16* la = &As[(srow + i * 8) * 64];
            u16* lb = &Bs[(srow + i * 8) * 64];
            gload_lds16(ga, la);
            gload_lds16(gb, lb);
        }
        asm volatile("s_waitcnt vmcnt(0)");
        __syncthreads();

#pragma unroll
        for (int kk = 0; kk < 2; ++kk) {
            bf16x8 af[4], bfr[4];
            int kc = kk * 4 + (l >> 4);
#pragma unroll
            for (int mi = 0; mi < 4; ++mi) {
                int row = wm + mi * 16 + (l & 15);
                af[mi] = *(const bf16x8*)&As[row * 64 + ((kc ^ (row & 7)) << 3)];
            }
#pragma unroll
            for (int ni = 0; ni < 4; ++ni) {
                int col = wn + ni * 16 + (l & 15);
                bfr[ni] = *(const bf16x8*)&Bs[col * 64 + ((kc ^ (col & 7)) << 3)];
            }
#pragma unroll
            for (int mi = 0; mi < 4; ++mi)
#pragma unroll
                for (int ni = 0; ni < 4; ++ni)
                    acc[mi][ni] = __builtin_amdgcn_mfma_f32_16x16x32_bf16(
                        af[mi], bfr[ni], acc[mi][ni], 0, 0, 0);
        }
        __syncthreads();
    }

    // epilogue: C/D layout col=lane&15, row=(lane>>4)*4+q  [m89]
#pragma unroll
    for (int mi = 0; mi < 4; ++mi) {
#pragma unroll
        for (int qq = 0; qq < 4; ++qq) {
            int row = m0 + wm + mi * 16 + (l >> 4) * 4 + qq;
            if (GUARD && row >= Mreal) continue;
#pragma unroll
            for (int ni = 0; ni < 4; ++ni) {
                int col = n0 + wn + ni * 16 + (l & 15);
                if (GUARD && col >= Nreal) continue;
                float v = acc[mi][ni][qq];
                if (OUT_BF16) ((u16*)Cv)[(size_t)row * ldc + col] = f2bf(v);
                else          ((float*)Cv)[(size_t)row * ldc + col] = v;
            }
        }
    }
}

// ---------------- combo GEMM: [h2 | xs3] = h1 @ [W2s | G]^T-style (B rows = out cols)
// B = wcomb [640][512]: rows 0..29 = W2s, 30..127 = 0, 128..639 = G = W2s^T W2s.
__global__ __launch_bounds__(256) void gemm_combo(
    const u16* __restrict__ A, const u16* __restrict__ B,
    float* __restrict__ h2, u16* __restrict__ xs3)
{
    __shared__ u16 As[128 * 64];
    __shared__ u16 Bs[128 * 64];
    const int t = threadIdx.x;
    const int w = t >> 6, l = t & 63;

    const int nwg = gridDim.x * gridDim.y;
    const int lin = blockIdx.y * gridDim.x + blockIdx.x;
    const int xcd = lin & 7, loc = lin >> 3;
    const int q = nwg >> 3, r = nwg & 7;
    const int swz = (xcd < r ? xcd * (q + 1) : r * (q + 1) + (xcd - r) * q) + loc;
    const int bx = swz % gridDim.x, by = swz / gridDim.x;

    const int m0 = by * 128, n0 = bx * 128;
    const int wm = (w >> 1) * 64, wn = (w & 1) * 64;
    const int srow = w << 5;
    const int lrow = l >> 3, lc = l & 7;

    f32x4 acc[4][4] = {};

    for (int kt = 0; kt < 512; kt += 64) {
#pragma unroll
        for (int i = 0; i < 4; ++i) {
            int row = srow + i * 8 + lrow;
            int gc = ((lc ^ (row & 7)) << 3);
            gload_lds16(A + (size_t)(m0 + row) * 512 + kt + gc, &As[(srow + i * 8) * 64]);
            gload_lds16(B + (size_t)(n0 + row) * 512 + kt + gc, &Bs[(srow + i * 8) * 64]);
        }
        asm volatile("s_waitcnt vmcnt(0)");
        __syncthreads();

#pragma unroll
        for (int kk = 0; kk < 2; ++kk) {
            bf16x8 af[4], bfr[4];
            int kc = kk * 4 + (l >> 4);
#pragma unroll
            for (int mi = 0; mi < 4; ++mi) {
                int row = wm + mi * 16 + (l & 15);
                af[mi] = *(const bf16x8*)&As[row * 64 + ((kc ^ (row & 7)) << 3)];
            }
#pragma unroll
            for (int ni = 0; ni < 4; ++ni) {
                int col = wn + ni * 16 + (l & 15);
                bfr[ni] = *(const bf16x8*)&Bs[col * 64 + ((kc ^ (col & 7)) << 3)];
            }
#pragma unroll
            for (int mi = 0; mi < 4; ++mi)
#pragma unroll
                for (int ni = 0; ni < 4; ++ni)
                    acc[mi][ni] = __builtin_amdgcn_mfma_f32_16x16x32_bf16(
                        af[mi], bfr[ni], acc[mi][ni], 0, 0, 0);
        }
        __syncthreads();
    }

#pragma unroll
    for (int mi = 0; mi < 4; ++mi) {
#pragma unroll
        for (int qq = 0; qq < 4; ++qq) {
            int row = m0 + wm + mi * 16 + (l >> 4) * 4 + qq;
#pragma unroll
            for (int ni = 0; ni < 4; ++ni) {
                int col = n0 + wn + ni * 16 + (l & 15);
                float v = acc[mi][ni][qq];
                if (col < 30) {
                    if (row < 30000) h2[(size_t)row * 30 + col] = v;
                } else if (col >= 128) {
                    xs3[(size_t)row * 512 + (col - 128)] = f2bf(v);
                }
            }
        }
    }
}

// ---------------- vd[i] = sum_h W1d[h,i]*a1d[h];  vs[i] = sum_h W1s[h,i]*a1s[h] ----
__global__ void k_vd(const float* __restrict__ W1d, const float* __restrict__ a1d,
                     const float* __restrict__ W1s, const float* __restrict__ a1s,
                     float* __restrict__ vd, float* __restrict__ vs) {
    int i = blockIdx.x * 256 + threadIdx.x;
    if (i >= 3000) return;
    float ad = 0.f, as = 0.f;
    for (int h = 0; h < 512; ++h) {
        ad += W1d[(size_t)h * 3000 + i] * a1d[h];
        as += W1s[(size_t)h * 3000 + i] * a1s[h];
    }
    vd[i] = ad;
    vs[i] = as;
}

// ---------------- W1s -> bf16 [512][3072] (K-pad) ----------------
__global__ void k_w1sb(const float* __restrict__ W1s, u16* __restrict__ wb) {
    int idx = blockIdx.x * 256 + threadIdx.x;
    if (idx >= 512 * 768) return;
    int n = idx / 768, g = idx % 768, k = g * 4;
    ushort4 o = make_ushort4(0, 0, 0, 0);
    if (k < 3000) {
        float4 v = *(const float4*)(W1s + (size_t)n * 3000 + k);
        o.x = f2bf(v.x); o.y = f2bf(v.y); o.z = f2bf(v.z); o.w = f2bf(v.w);
    }
    *(ushort4*)(wb + (size_t)n * 3072 + k) = o;
}

// ---------------- W1s^T -> bf16 [3072][512], LDS-tiled transpose ----------------
__global__ void k_w1st(const float* __restrict__ W1s, u16* __restrict__ wt) {
    __shared__ float tile[64][65];
    int t = threadIdx.x;
    int i0 = blockIdx.x * 64;      // 48 blocks -> i in [0,3072)
    int h0 = blockIdx.y * 64;      // 8 blocks  -> h in [0,512)
    int il = t & 63, hq = t >> 6;
#pragma unroll
    for (int rr = 0; rr < 16; ++rr) {
        int hl = rr * 4 + hq;
        int i = i0 + il;
        tile[hl][il] = (i < 3000) ? W1s[(size_t)(h0 + hl) * 3000 + i] : 0.f;
    }
    __syncthreads();
#pragma unroll
    for (int rr = 0; rr < 16; ++rr) {
        int il2 = rr * 4 + hq;
        wt[(size_t)(i0 + il2) * 512 + h0 + il] = f2bf(tile[il][il2]);
    }
}

// ---------------- wcomb [640][512]: rows<30 = W2s; rows in [128,640) = G ----------
__global__ void k_wcomb(const float* __restrict__ W2s, u16* __restrict__ wb) {
    int idx = blockIdx.x * 256 + threadIdx.x;
    if (idx >= 640 * 512) return;
    int n = idx >> 9, k = idx & 511;
    float v = 0.f;
    if (n < 30) {
        v = W2s[(size_t)n * 512 + k];
    } else if (n >= 128) {
        int i = n - 128;
        for (int o = 0; o < 30; ++o)
            v += W2s[(size_t)o * 512 + i] * W2s[(size_t)o * 512 + k];
    }
    wb[idx] = f2bf(v);
}

// ---------------- X fp32 -> bf16 padded [30080][3072], fused sd = X.vd, ss = X.vs --
__global__ void k_convX(const float* __restrict__ X, u16* __restrict__ xb,
                        const float* __restrict__ vd, const float* __restrict__ vs,
                        float* __restrict__ sd, float* __restrict__ ss) {
    __shared__ float redd[4], reds[4];
    int n = blockIdx.x, t = threadIdx.x;
    u16* brow = xb + (size_t)n * 3072;
    if (n < 30000) {
        const float* xrow = X + (size_t)n * 3000;
        float pd = 0.f, ps = 0.f;
#pragma unroll
        for (int it = 0; it < 3; ++it) {
            int c = (t + it * 256) * 4;
            ushort4 o = make_ushort4(0, 0, 0, 0);
            if (c < 3000) {
                float4 v = *(const float4*)(xrow + c);
                float4 wd = *(const float4*)(vd + c);
                float4 ws = *(const float4*)(vs + c);
                o.x = f2bf(v.x); o.y = f2bf(v.y); o.z = f2bf(v.z); o.w = f2bf(v.w);
                pd += v.x * wd.x + v.y * wd.y + v.z * wd.z + v.w * wd.w;
                ps += v.x * ws.x + v.y * ws.y + v.z * ws.z + v.w * ws.w;
            }
            *(ushort4*)(brow + c) = o;
        }
#pragma unroll
        for (int s = 32; s; s >>= 1) {
            pd += __shfl_xor(pd, s);
            ps += __shfl_xor(ps, s);
        }
        if ((t & 63) == 0) { redd[t >> 6] = pd; reds[t >> 6] = ps; }
        __syncthreads();
        if (t == 0) {
            sd[n] = redd[0] + redd[1] + redd[2] + redd[3];
            ss[n] = reds[0] + reds[1] + reds[2] + reds[3];
        }
    } else {
#pragma unroll
        for (int it = 0; it < 3; ++it)
            *(ushort4*)(brow + (t + it * 256) * 4) = make_ushort4(0, 0, 0, 0);
    }
}

// ---------------- CSR build ----------------
__global__ void k_deg(const int* __restrict__ dst, unsigned* __restrict__ deg) {
    int j = blockIdx.x * 256 + threadIdx.x;
    if (j < 180000) atomicAdd(&deg[dst[j]], 1u);
}

__global__ void k_scan1(const unsigned* __restrict__ deg, unsigned* __restrict__ bsum, int n) {
    __shared__ unsigned ws[4];
    int i = blockIdx.x * 256 + threadIdx.x;
    unsigned v = (i < n) ? deg[i] : 0u;
#pragma unroll
    for (int s = 32; s; s >>= 1) v += __shfl_xor(v, s);
    if ((threadIdx.x & 63) == 0) ws[threadIdx.x >> 6] = v;
    __syncthreads();
    if (threadIdx.x == 0) bsum[blockIdx.x] = ws[0] + ws[1] + ws[2] + ws[3];
}

__global__ void k_scan2(const unsigned* __restrict__ bsum, unsigned* __restrict__ boff,
                        unsigned* __restrict__ off_end, int nb) {
    __shared__ unsigned tmp[128];
    int t = threadIdx.x;
    unsigned v = (t < nb) ? bsum[t] : 0u;
    tmp[t] = v;
    __syncthreads();
    for (int s = 1; s < 128; s <<= 1) {
        unsigned a = (t >= s) ? tmp[t - s] : 0u;
        __syncthreads();
        tmp[t] += a;
        __syncthreads();
    }
    if (t < nb) boff[t] = tmp[t] - v;
    if (t == nb - 1) *off_end = tmp[t];
}

__global__ void k_scan3(const unsigned* __restrict__ deg, const unsigned* __restrict__ boff,
                        unsigned* __restrict__ off, unsigned* __restrict__ cur, int n) {
    __shared__ unsigned tmp[256];
    int b = blockIdx.x, t = threadIdx.x, i = b * 256 + t;
    unsigned v = (i < n) ? deg[i] : 0u;
    tmp[t] = v;
    __syncthreads();
    for (int s = 1; s < 256; s <<= 1) {
        unsigned a = (t >= s) ? tmp[t - s] : 0u;
        __syncthreads();
        tmp[t] += a;
        __syncthreads();
    }
    if (i < n) {
        unsigned o = boff[b] + tmp[t] - v;
        off[i] = o;
        cur[i] = o;
    }
}

__global__ void k_fill(const int* __restrict__ dst, unsigned* __restrict__ cur,
                       unsigned* __restrict__ csr) {
    int j = blockIdx.x * 256 + threadIdx.x;
    if (j >= 180000) return;
    unsigned pos = atomicAdd(&cur[dst[j]], 1u);
    csr[pos] = (unsigned)j;
}

// ---------------- fused score+softmax: alpha from ss/sd, 8-lane groups ----------
__global__ void k_soft(const int* __restrict__ src, const float* __restrict__ ss,
                       const float* __restrict__ sd, float* __restrict__ alpha,
                       const unsigned* __restrict__ csr, const unsigned* __restrict__ off) {
    int t = threadIdx.x;
    int g = t >> 3, l = t & 7;
    int n = blockIdx.x * 32 + g;
    if (n >= 30000) return;
    unsigned lo = off[n], hi = off[n + 1];
    if (lo == hi) return;
    float sdn = sd[n];
    float m = -1e30f;
    for (unsigned i = lo + l; i < hi; i += 8) {
        float v = ss[src[csr[i]]] + sdn;
        v = v > 0.f ? v : 0.2f * v;
        m = fmaxf(m, v);
    }
    m = fmaxf(m, __shfl_xor(m, 1));
    m = fmaxf(m, __shfl_xor(m, 2));
    m = fmaxf(m, __shfl_xor(m, 4));
    float den = 0.f;
    for (unsigned i = lo + l; i < hi; i += 8) {
        float v = ss[src[csr[i]]] + sdn;
        v = v > 0.f ? v : 0.2f * v;
        den += expf(v - m);
    }
    den += __shfl_xor(den, 1);
    den += __shfl_xor(den, 2);
    den += __shfl_xor(den, 4);
    float inv = 1.f / den;
    for (unsigned i = lo + l; i < hi; i += 8) {
        unsigned j = csr[i];
        float v = ss[src[j]] + sdn;
        v = v > 0.f ? v : 0.2f * v;
        alpha[j] = expf(v - m) * inv;
    }
}

// ---------------- aggregation + ELU: wave per node, bf16x8 loads ----------------
__global__ void k_agg(const u16* __restrict__ xin, const float* __restrict__ alpha,
                      const unsigned* __restrict__ csr, const unsigned* __restrict__ off,
                      const int* __restrict__ src, u16* __restrict__ outb, int nvalid) {
    int w = threadIdx.x >> 6, l = threadIdx.x & 63;
    int n = blockIdx.x * 4 + w;
    float acc[8] = {};
    if (n < nvalid) {
        unsigned lo = off[n], hi = off[n + 1];
        for (unsigned i = lo; i < hi; ++i) {
            unsigned j = csr[i];
            float av = alpha[j];
            int sj = src[j];
            u16x8 row = *(const u16x8*)&xin[(size_t)sj * 512 + l * 8];
#pragma unroll
            for (int k = 0; k < 8; ++k) acc[k] += av * bf2f(row[k]);
        }
    }
    u16x8 o;
#pragma unroll
    for (int k = 0; k < 8; ++k) {
        float a = acc[k] > 0.f ? acc[k] : expf(acc[k]) - 1.f;
        o[k] = f2bf(a);
    }
    *(u16x8*)&outb[(size_t)n * 512 + l * 8] = o;
}

extern "C" void kernel_launch(void* const* d_in, const int* in_sizes, int n_in,
                              void* d_out, int out_size, void* d_ws, size_t ws_size,
                              hipStream_t stream) {
    const float* X   = (const float*)d_in[0];
    const int*   ei  = (const int*)d_in[1];
    const float* W1s = (const float*)d_in[2];
    const float* W1d = (const float*)d_in[3];
    const float* a1s = (const float*)d_in[4];
    const float* a1d = (const float*)d_in[5];
    const float* W2s = (const float*)d_in[6];
    const int* src = ei;
    const int* dst = ei + 180000;

    float* out = (float*)d_out;
    float* h2 = out;               // [30000][30]
    float* h4 = out + 900000;      // [30000][3000]

    // scratch inside d_out h4 region (dead before gemm5 overwrites it)
    char* ob = (char*)(out + 900000);
    u16* xbf  = (u16*)ob;                                        // 30080*3072 bf16
    u16* xs1b = (u16*)(ob + 184811520);                          // 30080*512
    u16* h1b  = (u16*)(ob + 184811520 + 30801920);               // 30080*512
    u16* xs3b = (u16*)(ob + 184811520 + 30801920 + 30801920);    // 30080*512

    // ws scratch (must survive gemm5): h3b + W1sT + small vectors
    char* w = (char*)d_ws;
    auto carve = [&](size_t bytes) { char* p = w; w += (bytes + 255) & ~(size_t)255; return p; };
    u16* w1sb  = (u16*)carve((size_t)512 * 3072 * 2);
    u16* w1st  = (u16*)carve((size_t)3072 * 512 * 2);
    u16* wcomb = (u16*)carve((size_t)640 * 512 * 2);
    u16* h3b   = (u16*)carve((size_t)30080 * 512 * 2);
    float* vd    = (float*)carve(3008 * 4);
    float* vs    = (float*)carve(3008 * 4);
    float* ss    = (float*)carve(30000 * 4);
    float* sd    = (float*)carve(30000 * 4);
    float* alpha = (float*)carve(180000 * 4);
    unsigned* deg = (unsigned*)carve(30000 * 4);
    unsigned* off = (unsigned*)carve(30004 * 4);
    unsigned* cur = (unsigned*)carve(30000 * 4);
    unsigned* csr = (unsigned*)carve(180000 * 4);
    unsigned* bsum = (unsigned*)carve(128 * 4);
    unsigned* boff = (unsigned*)carve(128 * 4);

    hipMemsetAsync(deg, 0, 30000 * 4, stream);

    k_vd   <<<12, 256, 0, stream>>>(W1d, a1d, W1s, a1s, vd, vs);
    k_w1sb <<<1536, 256, 0, stream>>>(W1s, w1sb);
    k_w1st <<<dim3(48, 8), 256, 0, stream>>>(W1s, w1st);
    k_wcomb<<<1280, 256, 0, stream>>>(W2s, wcomb);
    k_convX<<<30080, 256, 0, stream>>>(X, xbf, vd, vs, sd, ss);

    gemm_bt<true, false><<<dim3(4, 235), 256, 0, stream>>>(xbf, w1sb, xs1b, 3072, 512, 0, 0);

    k_deg <<<704, 256, 0, stream>>>(dst, deg);
    k_scan1<<<118, 256, 0, stream>>>(deg, bsum, 30000);
    k_scan2<<<1, 128, 0, stream>>>(bsum, boff, &off[30000], 118);
    k_scan3<<<118, 256, 0, stream>>>(deg, boff, off, cur, 30000);
    k_fill<<<704, 256, 0, stream>>>(dst, cur, csr);
    k_soft<<<938, 256, 0, stream>>>(src, ss, sd, alpha, csr, off);

    k_agg <<<7520, 256, 0, stream>>>(xs1b, alpha, csr, off, src, h1b, 30000);

    // [h2 | xs3] = h1 @ [W2s | G]^T in one MFMA pass
    gemm_combo<<<dim3(5, 235), 256, 0, stream>>>(h1b, wcomb, h2, xs3b);

    k_agg <<<7520, 256, 0, stream>>>(xs3b, alpha, csr, off, src, h3b, 30000);

    gemm_bt<false, true><<<dim3(24, 235), 256, 0, stream>>>(h3b, w1st, h4, 512, 3000, 30000, 3000);
}

// Round 6
// 681.499 us; speedup vs baseline: 1.0634x; 1.0634x over previous
//
#include <hip/hip_runtime.h>

typedef unsigned short u16;
typedef __bf16 bf16_t;
typedef bf16_t bf16x8 __attribute__((ext_vector_type(8)));
typedef float f32x4 __attribute__((ext_vector_type(4)));
typedef u16 u16x8 __attribute__((ext_vector_type(8)));

#define AS1 __attribute__((address_space(1)))
#define AS3 __attribute__((address_space(3)))

__device__ __forceinline__ u16 f2bf(float f) {
    union { float f; unsigned u; } v; v.f = f;
    unsigned r = v.u + 0x7FFFu + ((v.u >> 16) & 1u);
    return (u16)(r >> 16);
}
__device__ __forceinline__ float bf2f(u16 s) {
    union { unsigned u; float f; } v; v.u = ((unsigned)s) << 16;
    return v.f;
}

__device__ __forceinline__ void gload_lds16(const u16* g, u16* l) {
    __builtin_amdgcn_global_load_lds((AS1 const void*)g, (AS3 void*)l, 16, 0, 0);
}

// ---------------- big GEMM: C[M,N] = A[M,K] * B[N,K]^T, bf16 in, 128x128 tile ----
// m97 structure + G4 XOR swizzle + T1 bijective XCD-chunked block swizzle (m204).
template <bool OUT_BF16, bool GUARD>
__global__ __launch_bounds__(256) void gemm_bt(
    const u16* __restrict__ A, const u16* __restrict__ B, void* __restrict__ Cv,
    int K, int ldc, int Mreal, int Nreal)
{
    __shared__ u16 As[128 * 64];
    __shared__ u16 Bs[128 * 64];
    const int t = threadIdx.x;
    const int w = t >> 6, l = t & 63;

    const int nwg = gridDim.x * gridDim.y;
    const int lin = blockIdx.y * gridDim.x + blockIdx.x;
    const int xcd = lin & 7, loc = lin >> 3;
    const int q = nwg >> 3, r = nwg & 7;
    const int swz = (xcd < r ? xcd * (q + 1) : r * (q + 1) + (xcd - r) * q) + loc;
    const int bx = swz % gridDim.x, by = swz / gridDim.x;

    const int m0 = by * 128, n0 = bx * 128;
    const int wm = (w >> 1) * 64, wn = (w & 1) * 64;

    const int srow = w << 5;           // wave's 32-row staging base
    const int lrow = l >> 3, lc = l & 7;

    f32x4 acc[4][4] = {};

    for (int kt = 0; kt < K; kt += 64) {
#pragma unroll
        for (int i = 0; i < 4; ++i) {
            int row = srow + i * 8 + lrow;
            int gc = ((lc ^ (row & 7)) << 3);
            const u16* ga = A + (size_t)(m0 + row) * K + kt + gc;
            const u16* gb = B + (size_t)(n0 + row) * K + kt + gc;
            u16* la = &As[(srow + i * 8) * 64];
            u16* lb = &Bs[(srow + i * 8) * 64];
            gload_lds16(ga, la);
            gload_lds16(gb, lb);
        }
        asm volatile("s_waitcnt vmcnt(0)");
        __syncthreads();

#pragma unroll
        for (int kk = 0; kk < 2; ++kk) {
            bf16x8 af[4], bfr[4];
            int kc = kk * 4 + (l >> 4);
#pragma unroll
            for (int mi = 0; mi < 4; ++mi) {
                int row = wm + mi * 16 + (l & 15);
                af[mi] = *(const bf16x8*)&As[row * 64 + ((kc ^ (row & 7)) << 3)];
            }
#pragma unroll
            for (int ni = 0; ni < 4; ++ni) {
                int col = wn + ni * 16 + (l & 15);
                bfr[ni] = *(const bf16x8*)&Bs[col * 64 + ((kc ^ (col & 7)) << 3)];
            }
#pragma unroll
            for (int mi = 0; mi < 4; ++mi)
#pragma unroll
                for (int ni = 0; ni < 4; ++ni)
                    acc[mi][ni] = __builtin_amdgcn_mfma_f32_16x16x32_bf16(
                        af[mi], bfr[ni], acc[mi][ni], 0, 0, 0);
        }
        __syncthreads();
    }

    // epilogue: C/D layout col=lane&15, row=(lane>>4)*4+q  [m89]
#pragma unroll
    for (int mi = 0; mi < 4; ++mi) {
#pragma unroll
        for (int qq = 0; qq < 4; ++qq) {
            int row = m0 + wm + mi * 16 + (l >> 4) * 4 + qq;
            if (GUARD && row >= Mreal) continue;
#pragma unroll
            for (int ni = 0; ni < 4; ++ni) {
                int col = n0 + wn + ni * 16 + (l & 15);
                if (GUARD && col >= Nreal) continue;
                float v = acc[mi][ni][qq];
                if (OUT_BF16) ((u16*)Cv)[(size_t)row * ldc + col] = f2bf(v);
                else          ((float*)Cv)[(size_t)row * ldc + col] = v;
            }
        }
    }
}

// ---------------- merged prep: vd/vs | w1sb | w1st | w2b | deg ----------------
// S0 [0,12): vd/vs matvecs      S1 [12,1516): W1s->bf16 [512][3008]
// S2 [1516,1900): W1s^T tiled   S3 [1900,2156): W2s->bf16 [128][512]
// S4 [2156,2860): deg atomics
__global__ void k_prep(const float* __restrict__ W1d, const float* __restrict__ a1d,
                       const float* __restrict__ W1s, const float* __restrict__ a1s,
                       const float* __restrict__ W2s, const int* __restrict__ dst,
                       float* __restrict__ vd, float* __restrict__ vs,
                       u16* __restrict__ w1sb, u16* __restrict__ w1st,
                       u16* __restrict__ w2sb, unsigned* __restrict__ deg) {
    int b = blockIdx.x, t = threadIdx.x;
    if (b < 12) {
        int i = b * 256 + t;
        if (i >= 3000) return;
        float ad = 0.f, as = 0.f;
        for (int h = 0; h < 512; ++h) {
            ad += W1d[(size_t)h * 3000 + i] * a1d[h];
            as += W1s[(size_t)h * 3000 + i] * a1s[h];
        }
        vd[i] = ad;
        vs[i] = as;
    } else if (b < 1516) {
        int idx = (b - 12) * 256 + t;          // 512*752
        int n = idx / 752, k = (idx % 752) * 4;
        ushort4 o = make_ushort4(0, 0, 0, 0);
        if (k < 3000) {
            float4 v = *(const float4*)(W1s + (size_t)n * 3000 + k);
            o.x = f2bf(v.x); o.y = f2bf(v.y); o.z = f2bf(v.z); o.w = f2bf(v.w);
        }
        *(ushort4*)(w1sb + (size_t)n * 3008 + k) = o;
    } else if (b < 1900) {
        __shared__ float tile[64][65];
        int fb = b - 1516;
        int i0 = (fb % 48) * 64, h0 = (fb / 48) * 64;
        int il = t & 63, hq = t >> 6;
#pragma unroll
        for (int rr = 0; rr < 16; ++rr) {
            int hl = rr * 4 + hq;
            int i = i0 + il;
            tile[hl][il] = (i < 3000) ? W1s[(size_t)(h0 + hl) * 3000 + i] : 0.f;
        }
        __syncthreads();
#pragma unroll
        for (int rr = 0; rr < 16; ++rr) {
            int il2 = rr * 4 + hq;
            w1st[(size_t)(i0 + il2) * 512 + h0 + il] = f2bf(tile[il][il2]);
        }
    } else if (b < 2156) {
        int idx = (b - 1900) * 256 + t;        // 128*512
        int n = idx >> 9, k = idx & 511;
        w2sb[idx] = (n < 30) ? f2bf(W2s[(size_t)n * 512 + k]) : (u16)0;
    } else {
        int j = (b - 2156) * 256 + t;
        if (j < 180000) atomicAdd(&deg[dst[j]], 1u);
    }
}

// ---------------- X fp32 -> bf16 padded [30080][3008], fused sd = X.vd, ss = X.vs --
__global__ void k_convX(const float* __restrict__ X, u16* __restrict__ xb,
                        const float* __restrict__ vd, const float* __restrict__ vs,
                        float* __restrict__ sd, float* __restrict__ ss) {
    __shared__ float redd[4], reds[4];
    int n = blockIdx.x, t = threadIdx.x;
    u16* brow = xb + (size_t)n * 3008;
    if (n < 30000) {
        const float* xrow = X + (size_t)n * 3000;
        float pd = 0.f, ps = 0.f;
#pragma unroll
        for (int it = 0; it < 3; ++it) {
            int c = (t + it * 256) * 4;
            if (c < 3000) {
                float4 v = *(const float4*)(xrow + c);
                float4 wd = *(const float4*)(vd + c);
                float4 wvs = *(const float4*)(vs + c);
                ushort4 o;
                o.x = f2bf(v.x); o.y = f2bf(v.y); o.z = f2bf(v.z); o.w = f2bf(v.w);
                pd += v.x * wd.x + v.y * wd.y + v.z * wd.z + v.w * wd.w;
                ps += v.x * wvs.x + v.y * wvs.y + v.z * wvs.z + v.w * wvs.w;
                *(ushort4*)(brow + c) = o;
            } else if (c < 3008) {
                *(ushort4*)(brow + c) = make_ushort4(0, 0, 0, 0);
            }
        }
#pragma unroll
        for (int s = 32; s; s >>= 1) {
            pd += __shfl_xor(pd, s);
            ps += __shfl_xor(ps, s);
        }
        if ((t & 63) == 0) { redd[t >> 6] = pd; reds[t >> 6] = ps; }
        __syncthreads();
        if (t == 0) {
            sd[n] = redd[0] + redd[1] + redd[2] + redd[3];
            ss[n] = reds[0] + reds[1] + reds[2] + reds[3];
        }
    } else {
#pragma unroll
        for (int it = 0; it < 3; ++it) {
            int c = (t + it * 256) * 4;
            if (c < 3008) *(ushort4*)(brow + c) = make_ushort4(0, 0, 0, 0);
        }
    }
}

// ---------------- scan stage 1: per-block sums ----------------
__global__ void k_scan1(const unsigned* __restrict__ deg, unsigned* __restrict__ bsum, int n) {
    __shared__ unsigned ws[4];
    int i = blockIdx.x * 256 + threadIdx.x;
    unsigned v = (i < n) ? deg[i] : 0u;
#pragma unroll
    for (int s = 32; s; s >>= 1) v += __shfl_xor(v, s);
    if ((threadIdx.x & 63) == 0) ws[threadIdx.x >> 6] = v;
    __syncthreads();
    if (threadIdx.x == 0) bsum[blockIdx.x] = ws[0] + ws[1] + ws[2] + ws[3];
}

// ---------------- scan stage 2: per-block offset via masked wave-sum + local scan --
__global__ void k_scanB(const unsigned* __restrict__ deg, const unsigned* __restrict__ bsum,
                        unsigned* __restrict__ off, unsigned* __restrict__ cur,
                        int n, int nb) {
    __shared__ unsigned tmp[256];
    __shared__ unsigned bo;
    int b = blockIdx.x, t = threadIdx.x, i = b * 256 + t;
    if (t < 64) {
        unsigned s0 = (t < nb) ? bsum[t] : 0u;
        unsigned s1 = (t + 64 < nb) ? bsum[t + 64] : 0u;
        unsigned v = ((t < b) ? s0 : 0u) + ((t + 64 < b) ? s1 : 0u);
#pragma unroll
        for (int s = 32; s; s >>= 1) v += __shfl_xor(v, s);
        if (t == 0) bo = v;
        if (b == nb - 1) {
            unsigned tv = s0 + s1;
#pragma unroll
            for (int s = 32; s; s >>= 1) tv += __shfl_xor(tv, s);
            if (t == 0) off[n] = tv;
        }
    }
    __syncthreads();
    unsigned v = (i < n) ? deg[i] : 0u;
    tmp[t] = v;
    __syncthreads();
    for (int s = 1; s < 256; s <<= 1) {
        unsigned a = (t >= s) ? tmp[t - s] : 0u;
        __syncthreads();
        tmp[t] += a;
        __syncthreads();
    }
    if (i < n) {
        unsigned o = bo + tmp[t] - v;
        off[i] = o;
        cur[i] = o;
    }
}

__global__ void k_fill(const int* __restrict__ dst, unsigned* __restrict__ cur,
                       unsigned* __restrict__ csr) {
    int j = blockIdx.x * 256 + threadIdx.x;
    if (j >= 180000) return;
    unsigned pos = atomicAdd(&cur[dst[j]], 1u);
    csr[pos] = (unsigned)j;
}

// ---------------- fused score+softmax: alpha from ss/sd, 8-lane groups ----------
__global__ void k_soft(const int* __restrict__ src, const float* __restrict__ ss,
                       const float* __restrict__ sd, float* __restrict__ alpha,
                       const unsigned* __restrict__ csr, const unsigned* __restrict__ off) {
    int t = threadIdx.x;
    int g = t >> 3, l = t & 7;
    int n = blockIdx.x * 32 + g;
    if (n >= 30000) return;
    unsigned lo = off[n], hi = off[n + 1];
    if (lo == hi) return;
    float sdn = sd[n];
    float m = -1e30f;
    for (unsigned i = lo + l; i < hi; i += 8) {
        float v = ss[src[csr[i]]] + sdn;
        v = v > 0.f ? v : 0.2f * v;
        m = fmaxf(m, v);
    }
    m = fmaxf(m, __shfl_xor(m, 1));
    m = fmaxf(m, __shfl_xor(m, 2));
    m = fmaxf(m, __shfl_xor(m, 4));
    float den = 0.f;
    for (unsigned i = lo + l; i < hi; i += 8) {
        float v = ss[src[csr[i]]] + sdn;
        v = v > 0.f ? v : 0.2f * v;
        den += expf(v - m);
    }
    den += __shfl_xor(den, 1);
    den += __shfl_xor(den, 2);
    den += __shfl_xor(den, 4);
    float inv = 1.f / den;
    for (unsigned i = lo + l; i < hi; i += 8) {
        unsigned j = csr[i];
        float v = ss[src[j]] + sdn;
        v = v > 0.f ? v : 0.2f * v;
        alpha[j] = expf(v - m) * inv;
    }
}

// ---------------- aggregation + ELU: wave per node, 2-edge pipelined gathers ------
__global__ void k_agg(const u16* __restrict__ xin, const float* __restrict__ alpha,
                      const unsigned* __restrict__ csr, const unsigned* __restrict__ off,
                      const int* __restrict__ src, u16* __restrict__ outb, int nvalid) {
    int w = threadIdx.x >> 6, l = threadIdx.x & 63;
    int n = blockIdx.x * 4 + w;
    float acc[8] = {};
    if (n < nvalid) {
        unsigned lo = off[n], hi = off[n + 1];
        unsigned i = lo;
        for (; i + 2 <= hi; i += 2) {
            unsigned j0 = csr[i], j1 = csr[i + 1];
            float a0 = alpha[j0], a1 = alpha[j1];
            int s0 = src[j0], s1 = src[j1];
            u16x8 r0 = *(const u16x8*)&xin[(size_t)s0 * 512 + l * 8];
            u16x8 r1 = *(const u16x8*)&xin[(size_t)s1 * 512 + l * 8];
#pragma unroll
            for (int k = 0; k < 8; ++k) acc[k] += a0 * bf2f(r0[k]) + a1 * bf2f(r1[k]);
        }
        if (i < hi) {
            unsigned j0 = csr[i];
            float a0 = alpha[j0];
            int s0 = src[j0];
            u16x8 r0 = *(const u16x8*)&xin[(size_t)s0 * 512 + l * 8];
#pragma unroll
            for (int k = 0; k < 8; ++k) acc[k] += a0 * bf2f(r0[k]);
        }
    }
    u16x8 o;
#pragma unroll
    for (int k = 0; k < 8; ++k) {
        float a = acc[k] > 0.f ? acc[k] : expf(acc[k]) - 1.f;
        o[k] = f2bf(a);
    }
    *(u16x8*)&outb[(size_t)n * 512 + l * 8] = o;
}

// ---------------- xs3[n,h] = h2[n,:] . W2s[:,h]  (K=30) -> bf16 ----------------
__global__ void k_xs3(const float* __restrict__ h2, const float* __restrict__ W2s,
                      u16* __restrict__ xs3) {
    int t = threadIdx.x;
    size_t n0 = (size_t)blockIdx.x * 8;
    float w0[30], w1[30];
#pragma unroll
    for (int o = 0; o < 30; ++o) {
        w0[o] = W2s[(size_t)o * 512 + t];
        w1[o] = W2s[(size_t)o * 512 + t + 256];
    }
    for (int r = 0; r < 8; ++r) {
        size_t n = n0 + r;
        const float* hr = h2 + n * 30;
        float a0 = 0.f, a1 = 0.f;
#pragma unroll
        for (int o = 0; o < 30; ++o) {
            float v = hr[o];
            a0 += v * w0[o];
            a1 += v * w1[o];
        }
        xs3[n * 512 + t] = f2bf(a0);
        xs3[n * 512 + t + 256] = f2bf(a1);
    }
}

extern "C" void kernel_launch(void* const* d_in, const int* in_sizes, int n_in,
                              void* d_out, int out_size, void* d_ws, size_t ws_size,
                              hipStream_t stream) {
    const float* X   = (const float*)d_in[0];
    const int*   ei  = (const int*)d_in[1];
    const float* W1s = (const float*)d_in[2];
    const float* W1d = (const float*)d_in[3];
    const float* a1s = (const float*)d_in[4];
    const float* a1d = (const float*)d_in[5];
    const float* W2s = (const float*)d_in[6];
    const int* src = ei;
    const int* dst = ei + 180000;

    float* out = (float*)d_out;
    float* h2 = out;               // [30000][30]
    float* h4 = out + 900000;      // [30000][3000]

    // scratch inside d_out h4 region (dead before gemm5 overwrites it)
    char* ob = (char*)(out + 900000);
    u16* xbf  = (u16*)ob;                                        // 30080*3008 bf16
    u16* xs1b = (u16*)(ob + 180961280);                          // 30080*512
    u16* h1b  = (u16*)(ob + 180961280 + 30801920);               // 30080*512
    u16* xs3b = (u16*)(ob + 180961280 + 30801920 + 30801920);    // 30080*512

    // ws scratch (must survive gemm5): h3b + W1sT + small vectors
    char* w = (char*)d_ws;
    auto carve = [&](size_t bytes) { char* p = w; w += (bytes + 255) & ~(size_t)255; return p; };
    u16* w1sb  = (u16*)carve((size_t)512 * 3008 * 2);
    u16* w1st  = (u16*)carve((size_t)3072 * 512 * 2);
    u16* w2sb  = (u16*)carve((size_t)128 * 512 * 2);
    u16* h3b   = (u16*)carve((size_t)30080 * 512 * 2);
    float* vd    = (float*)carve(3008 * 4);
    float* vs    = (float*)carve(3008 * 4);
    float* ss    = (float*)carve(30000 * 4);
    float* sd    = (float*)carve(30000 * 4);
    float* alpha = (float*)carve(180000 * 4);
    unsigned* deg = (unsigned*)carve(30000 * 4);
    unsigned* off = (unsigned*)carve(30004 * 4);
    unsigned* cur = (unsigned*)carve(30000 * 4);
    unsigned* csr = (unsigned*)carve(180000 * 4);
    unsigned* bsum = (unsigned*)carve(128 * 4);

    hipMemsetAsync(deg, 0, 30000 * 4, stream);

    // merged prep: vd/vs | w1sb | w1st | w2sb | deg
    k_prep<<<2860, 256, 0, stream>>>(W1d, a1d, W1s, a1s, W2s, dst,
                                     vd, vs, w1sb, w1st, w2sb, deg);

    k_convX<<<30080, 256, 0, stream>>>(X, xbf, vd, vs, sd, ss);

    gemm_bt<true, false><<<dim3(4, 235), 256, 0, stream>>>(xbf, w1sb, xs1b, 3008, 512, 0, 0);

    k_scan1<<<118, 256, 0, stream>>>(deg, bsum, 30000);
    k_scanB<<<118, 256, 0, stream>>>(deg, bsum, off, cur, 30000, 118);
    k_fill<<<704, 256, 0, stream>>>(dst, cur, csr);
    k_soft<<<938, 256, 0, stream>>>(src, ss, sd, alpha, csr, off);

    k_agg <<<7520, 256, 0, stream>>>(xs1b, alpha, csr, off, src, h1b, 30000);

    // h2 = h1 @ W2s.T via MFMA
    gemm_bt<false, true><<<dim3(1, 235), 256, 0, stream>>>(h1b, w2sb, h2, 512, 30, 30000, 30);

    k_xs3 <<<3750, 256, 0, stream>>>(h2, W2s, xs3b);
    k_agg <<<7520, 256, 0, stream>>>(xs3b, alpha, csr, off, src, h3b, 30000);

    gemm_bt<false, true><<<dim3(24, 235), 256, 0, stream>>>(h3b, w1st, h4, 512, 3000, 30000, 3000);
}

// Round 7
// 645.475 us; speedup vs baseline: 1.1227x; 1.0558x over previous
//
#include <hip/hip_runtime.h>

typedef unsigned short u16;
typedef __bf16 bf16_t;
typedef bf16_t bf16x8 __attribute__((ext_vector_type(8)));
typedef float f32x4 __attribute__((ext_vector_type(4)));
typedef u16 u16x8 __attribute__((ext_vector_type(8)));

#define AS1 __attribute__((address_space(1)))
#define AS3 __attribute__((address_space(3)))

__device__ __forceinline__ u16 f2bf(float f) {
    union { float f; unsigned u; } v; v.f = f;
    unsigned r = v.u + 0x7FFFu + ((v.u >> 16) & 1u);
    return (u16)(r >> 16);
}
__device__ __forceinline__ float bf2f(u16 s) {
    union { unsigned u; float f; } v; v.u = ((unsigned)s) << 16;
    return v.f;
}

__device__ __forceinline__ void gload_lds16(const u16* g, u16* l) {
    __builtin_amdgcn_global_load_lds((AS1 const void*)g, (AS3 void*)l, 16, 0, 0);
}

// ---------------- big GEMM: C[M,N] = A[M,K] * B[N,K]^T, bf16 in, 128x128 tile ----
// m97 structure + G4 XOR swizzle + T1 bijective XCD-chunked block swizzle (m204).
template <bool OUT_BF16, bool GUARD>
__global__ __launch_bounds__(256) void gemm_bt(
    const u16* __restrict__ A, const u16* __restrict__ B, void* __restrict__ Cv,
    int K, int ldc, int Mreal, int Nreal)
{
    __shared__ u16 As[128 * 64];
    __shared__ u16 Bs[128 * 64];
    const int t = threadIdx.x;
    const int w = t >> 6, l = t & 63;

    const int nwg = gridDim.x * gridDim.y;
    const int lin = blockIdx.y * gridDim.x + blockIdx.x;
    const int xcd = lin & 7, loc = lin >> 3;
    const int q = nwg >> 3, r = nwg & 7;
    const int swz = (xcd < r ? xcd * (q + 1) : r * (q + 1) + (xcd - r) * q) + loc;
    const int bx = swz % gridDim.x, by = swz / gridDim.x;

    const int m0 = by * 128, n0 = bx * 128;
    const int wm = (w >> 1) * 64, wn = (w & 1) * 64;

    const int srow = w << 5;           // wave's 32-row staging base
    const int lrow = l >> 3, lc = l & 7;

    f32x4 acc[4][4] = {};

    for (int kt = 0; kt < K; kt += 64) {
#pragma unroll
        for (int i = 0; i < 4; ++i) {
            int row = srow + i * 8 + lrow;
            int gc = ((lc ^ (row & 7)) << 3);
            const u16* ga = A + (size_t)(m0 + row) * K + kt + gc;
            const u16* gb = B + (size_t)(n0 + row) * K + kt + gc;
            u16* la = &As[(srow + i * 8) * 64];
            u16* lb = &Bs[(srow + i * 8) * 64];
            gload_lds16(ga, la);
            gload_lds16(gb, lb);
        }
        asm volatile("s_waitcnt vmcnt(0)");
        __syncthreads();

#pragma unroll
        for (int kk = 0; kk < 2; ++kk) {
            bf16x8 af[4], bfr[4];
            int kc = kk * 4 + (l >> 4);
#pragma unroll
            for (int mi = 0; mi < 4; ++mi) {
                int row = wm + mi * 16 + (l & 15);
                af[mi] = *(const bf16x8*)&As[row * 64 + ((kc ^ (row & 7)) << 3)];
            }
#pragma unroll
            for (int ni = 0; ni < 4; ++ni) {
                int col = wn + ni * 16 + (l & 15);
                bfr[ni] = *(const bf16x8*)&Bs[col * 64 + ((kc ^ (col & 7)) << 3)];
            }
#pragma unroll
            for (int mi = 0; mi < 4; ++mi)
#pragma unroll
                for (int ni = 0; ni < 4; ++ni)
                    acc[mi][ni] = __builtin_amdgcn_mfma_f32_16x16x32_bf16(
                        af[mi], bfr[ni], acc[mi][ni], 0, 0, 0);
        }
        __syncthreads();
    }

    // epilogue: C/D layout col=lane&15, row=(lane>>4)*4+q  [m89]
#pragma unroll
    for (int mi = 0; mi < 4; ++mi) {
#pragma unroll
        for (int qq = 0; qq < 4; ++qq) {
            int row = m0 + wm + mi * 16 + (l >> 4) * 4 + qq;
            if (GUARD && row >= Mreal) continue;
#pragma unroll
            for (int ni = 0; ni < 4; ++ni) {
                int col = n0 + wn + ni * 16 + (l & 15);
                if (GUARD && col >= Nreal) continue;
                float v = acc[mi][ni][qq];
                if (OUT_BF16) ((u16*)Cv)[(size_t)row * ldc + col] = f2bf(v);
                else          ((float*)Cv)[(size_t)row * ldc + col] = v;
            }
        }
    }
}

// ---------------- fused conv+GEMM1 v2: xs1 = bf16(X) @ W1s^T, sd/ss = X.vd/vs ----
// A: fp32 reg-prefetched one iter ahead, cvt->LDS. B: gload_lds, double-buffered,
// issued one iter ahead. One counted vmcnt(12) per iter; B(t) is never among the
// 12 newest ops so the count is robust to scheduler interleave.
__global__ __launch_bounds__(256) void gemm_xw2(
    const float* __restrict__ X, const u16* __restrict__ Bw, u16* __restrict__ C,
    const float* __restrict__ vd, const float* __restrict__ vs,
    float* __restrict__ sd, float* __restrict__ ss)
{
    __shared__ u16 As[128 * 64];
    __shared__ u16 Bs[2][128 * 64];
    const int t = threadIdx.x;
    const int w = t >> 6, l = t & 63;

    const int nwg = gridDim.x * gridDim.y;   // (4,235)
    const int lin = blockIdx.y * gridDim.x + blockIdx.x;
    const int xcd = lin & 7, loc = lin >> 3;
    const int q = nwg >> 3, r = nwg & 7;
    const int swz = (xcd < r ? xcd * (q + 1) : r * (q + 1) + (xcd - r) * q) + loc;
    const int bx = swz % gridDim.x, by = swz / gridDim.x;

    const int m0 = by * 128, n0 = bx * 128;
    const int wm = (w >> 1) * 64, wn = (w & 1) * 64;
    const int srow = w << 5;
    const int lrow = l >> 3, lc = l & 7;

    f32x4 acc[4][4] = {};
    float sdp[4] = {}, ssp[4] = {};
    const bool do_s = (bx == 0);

    int rowg[4];
    bool okr[4];
#pragma unroll
    for (int i = 0; i < 4; ++i) {
        rowg[i] = m0 + srow + i * 8 + lrow;
        okr[i] = rowg[i] < 30000;
    }

    float4 pa[4][2];
    auto loadA = [&](int kt) {
        int c = kt + lc * 8;
        bool okc = c < 3000;
#pragma unroll
        for (int i = 0; i < 4; ++i) {
            bool ok = okr[i] && okc;
            const float* p = X + (ok ? ((size_t)rowg[i] * 3000 + c) : 0);
            float4 v0 = *(const float4*)p;
            float4 v1 = *(const float4*)(p + 4);
            if (!ok) { v0 = make_float4(0.f, 0.f, 0.f, 0.f); v1 = v0; }
            pa[i][0] = v0;
            pa[i][1] = v1;
        }
    };
    auto stageB = [&](int kt2, int buf) {
#pragma unroll
        for (int i = 0; i < 4; ++i) {
            int row = srow + i * 8 + lrow;
            int gc = ((lc ^ (row & 7)) << 3);
            gload_lds16(Bw + (size_t)(n0 + row) * 3008 + kt2 + gc,
                        &Bs[buf][(srow + i * 8) * 64]);
        }
    };

    loadA(0);            // A(0) -> regs   [8 vm]
    stageB(0, 0);        // B(0) -> Bs[0]  [4 vm]
    int cur = 0;

    for (int kt = 0; kt < 3008; kt += 64) {
        // sd/ss partials from current A regs (block-uniform branch)
        if (do_s) {
            int c = kt + lc * 8;
            float4 d0 = *(const float4*)(vd + c);
            float4 d1 = *(const float4*)(vd + c + 4);
            float4 s0 = *(const float4*)(vs + c);
            float4 s1 = *(const float4*)(vs + c + 4);
#pragma unroll
            for (int i = 0; i < 4; ++i) {
                sdp[i] += pa[i][0].x * d0.x + pa[i][0].y * d0.y + pa[i][0].z * d0.z + pa[i][0].w * d0.w
                        + pa[i][1].x * d1.x + pa[i][1].y * d1.y + pa[i][1].z * d1.z + pa[i][1].w * d1.w;
                ssp[i] += pa[i][0].x * s0.x + pa[i][0].y * s0.y + pa[i][0].z * s0.z + pa[i][0].w * s0.w
                        + pa[i][1].x * s1.x + pa[i][1].y * s1.y + pa[i][1].z * s1.z + pa[i][1].w * s1.w;
            }
        }
        // convert current A -> As (swizzled)
#pragma unroll
        for (int i = 0; i < 4; ++i) {
            int row = srow + i * 8 + lrow;
            u16x8 o;
            o[0] = f2bf(pa[i][0].x); o[1] = f2bf(pa[i][0].y);
            o[2] = f2bf(pa[i][0].z); o[3] = f2bf(pa[i][0].w);
            o[4] = f2bf(pa[i][1].x); o[5] = f2bf(pa[i][1].y);
            o[6] = f2bf(pa[i][1].z); o[7] = f2bf(pa[i][1].w);
            *(u16x8*)&As[row * 64 + ((lc ^ (row & 7)) << 3)] = o;
        }
        // prefetch next tile: A -> regs, B -> other LDS buffer
        loadA(kt + 64);
        int ktn = (kt + 64 < 3008) ? kt + 64 : 2944;   // clamped harmless refetch
        stageB(ktn, cur ^ 1);
        // drain everything older than the 12 just-issued prefetch ops:
        // guarantees B(t) gloads + own ds_writes complete; keeps prefetch in flight
        asm volatile("s_waitcnt vmcnt(12) lgkmcnt(0)" ::: "memory");
        __builtin_amdgcn_s_barrier();

#pragma unroll
        for (int kk = 0; kk < 2; ++kk) {
            bf16x8 af[4], bfr[4];
            int kc = kk * 4 + (l >> 4);
#pragma unroll
            for (int mi = 0; mi < 4; ++mi) {
                int row = wm + mi * 16 + (l & 15);
                af[mi] = *(const bf16x8*)&As[row * 64 + ((kc ^ (row & 7)) << 3)];
            }
#pragma unroll
            for (int ni = 0; ni < 4; ++ni) {
                int col = wn + ni * 16 + (l & 15);
                bfr[ni] = *(const bf16x8*)&Bs[cur][col * 64 + ((kc ^ (col & 7)) << 3)];
            }
#pragma unroll
            for (int mi = 0; mi < 4; ++mi)
#pragma unroll
                for (int ni = 0; ni < 4; ++ni)
                    acc[mi][ni] = __builtin_amdgcn_mfma_f32_16x16x32_bf16(
                        af[mi], bfr[ni], acc[mi][ni], 0, 0, 0);
        }
        asm volatile("s_barrier" ::: "memory");   // reads done before next writes
        cur ^= 1;
    }

    // sd/ss: reduce over the 8 lanes sharing a row
    if (do_s) {
#pragma unroll
        for (int i = 0; i < 4; ++i) {
            float a = sdp[i], b = ssp[i];
            a += __shfl_xor(a, 1); a += __shfl_xor(a, 2); a += __shfl_xor(a, 4);
            b += __shfl_xor(b, 1); b += __shfl_xor(b, 2); b += __shfl_xor(b, 4);
            if (lc == 0 && okr[i]) { sd[rowg[i]] = a; ss[rowg[i]] = b; }
        }
    }

#pragma unroll
    for (int mi = 0; mi < 4; ++mi)
#pragma unroll
        for (int qq = 0; qq < 4; ++qq) {
            int row = m0 + wm + mi * 16 + (l >> 4) * 4 + qq;
#pragma unroll
            for (int ni = 0; ni < 4; ++ni) {
                int col = n0 + wn + ni * 16 + (l & 15);
                C[(size_t)row * 512 + col] = f2bf(acc[mi][qq == 0 ? ni : ni][qq]);
            }
        }
}

// ---------------- merged prep: vd/vs | w1sb | w1st | w2b | deg ----------------
__global__ void k_prep(const float* __restrict__ W1d, const float* __restrict__ a1d,
                       const float* __restrict__ W1s, const float* __restrict__ a1s,
                       const float* __restrict__ W2s, const int* __restrict__ dst,
                       float* __restrict__ vd, float* __restrict__ vs,
                       u16* __restrict__ w1sb, u16* __restrict__ w1st,
                       u16* __restrict__ w2sb, unsigned* __restrict__ deg) {
    int b = blockIdx.x, t = threadIdx.x;
    if (b < 12) {
        int i = b * 256 + t;
        if (i >= 3000) return;
        float ad = 0.f, as = 0.f;
        for (int h = 0; h < 512; ++h) {
            ad += W1d[(size_t)h * 3000 + i] * a1d[h];
            as += W1s[(size_t)h * 3000 + i] * a1s[h];
        }
        vd[i] = ad;
        vs[i] = as;
    } else if (b < 1516) {
        int idx = (b - 12) * 256 + t;          // 512*752
        int n = idx / 752, k = (idx % 752) * 4;
        ushort4 o = make_ushort4(0, 0, 0, 0);
        if (k < 3000) {
            float4 v = *(const float4*)(W1s + (size_t)n * 3000 + k);
            o.x = f2bf(v.x); o.y = f2bf(v.y); o.z = f2bf(v.z); o.w = f2bf(v.w);
        }
        *(ushort4*)(w1sb + (size_t)n * 3008 + k) = o;
    } else if (b < 1900) {
        __shared__ float tile[64][65];
        int fb = b - 1516;
        int i0 = (fb % 48) * 64, h0 = (fb / 48) * 64;
        int il = t & 63, hq = t >> 6;
#pragma unroll
        for (int rr = 0; rr < 16; ++rr) {
            int hl = rr * 4 + hq;
            int i = i0 + il;
            tile[hl][il] = (i < 3000) ? W1s[(size_t)(h0 + hl) * 3000 + i] : 0.f;
        }
        __syncthreads();
#pragma unroll
        for (int rr = 0; rr < 16; ++rr) {
            int il2 = rr * 4 + hq;
            w1st[(size_t)(i0 + il2) * 512 + h0 + il] = f2bf(tile[il][il2]);
        }
    } else if (b < 2156) {
        int idx = (b - 1900) * 256 + t;        // 128*512
        int n = idx >> 9, k = idx & 511;
        w2sb[idx] = (n < 30) ? f2bf(W2s[(size_t)n * 512 + k]) : (u16)0;
    } else {
        int j = (b - 2156) * 256 + t;
        if (j < 180000) atomicAdd(&deg[dst[j]], 1u);
    }
}

// ---------------- scan stage 1: per-block sums ----------------
__global__ void k_scan1(const unsigned* __restrict__ deg, unsigned* __restrict__ bsum, int n) {
    __shared__ unsigned ws[4];
    int i = blockIdx.x * 256 + threadIdx.x;
    unsigned v = (i < n) ? deg[i] : 0u;
#pragma unroll
    for (int s = 32; s; s >>= 1) v += __shfl_xor(v, s);
    if ((threadIdx.x & 63) == 0) ws[threadIdx.x >> 6] = v;
    __syncthreads();
    if (threadIdx.x == 0) bsum[blockIdx.x] = ws[0] + ws[1] + ws[2] + ws[3];
}

// ---------------- scan stage 2: per-block offset via masked wave-sum + local scan --
__global__ void k_scanB(const unsigned* __restrict__ deg, const unsigned* __restrict__ bsum,
                        unsigned* __restrict__ off, unsigned* __restrict__ cur,
                        int n, int nb) {
    __shared__ unsigned tmp[256];
    __shared__ unsigned bo;
    int b = blockIdx.x, t = threadIdx.x, i = b * 256 + t;
    if (t < 64) {
        unsigned s0 = (t < nb) ? bsum[t] : 0u;
        unsigned s1 = (t + 64 < nb) ? bsum[t + 64] : 0u;
        unsigned v = ((t < b) ? s0 : 0u) + ((t + 64 < b) ? s1 : 0u);
#pragma unroll
        for (int s = 32; s; s >>= 1) v += __shfl_xor(v, s);
        if (t == 0) bo = v;
        if (b == nb - 1) {
            unsigned tv = s0 + s1;
#pragma unroll
            for (int s = 32; s; s >>= 1) tv += __shfl_xor(tv, s);
            if (t == 0) off[n] = tv;
        }
    }
    __syncthreads();
    unsigned v = (i < n) ? deg[i] : 0u;
    tmp[t] = v;
    __syncthreads();
    for (int s = 1; s < 256; s <<= 1) {
        unsigned a = (t >= s) ? tmp[t - s] : 0u;
        __syncthreads();
        tmp[t] += a;
        __syncthreads();
    }
    if (i < n) {
        unsigned o = bo + tmp[t] - v;
        off[i] = o;
        cur[i] = o;
    }
}

__global__ void k_fill(const int* __restrict__ dst, unsigned* __restrict__ cur,
                       unsigned* __restrict__ csr) {
    int j = blockIdx.x * 256 + threadIdx.x;
    if (j >= 180000) return;
    unsigned pos = atomicAdd(&cur[dst[j]], 1u);
    csr[pos] = (unsigned)j;
}

// ---------------- fused score+softmax: alpha from ss/sd, 8-lane groups ----------
__global__ void k_soft(const int* __restrict__ src, const float* __restrict__ ss,
                       const float* __restrict__ sd, float* __restrict__ alpha,
                       const unsigned* __restrict__ csr, const unsigned* __restrict__ off) {
    int t = threadIdx.x;
    int g = t >> 3, l = t & 7;
    int n = blockIdx.x * 32 + g;
    if (n >= 30000) return;
    unsigned lo = off[n], hi = off[n + 1];
    if (lo == hi) return;
    float sdn = sd[n];
    float m = -1e30f;
    for (unsigned i = lo + l; i < hi; i += 8) {
        float v = ss[src[csr[i]]] + sdn;
        v = v > 0.f ? v : 0.2f * v;
        m = fmaxf(m, v);
    }
    m = fmaxf(m, __shfl_xor(m, 1));
    m = fmaxf(m, __shfl_xor(m, 2));
    m = fmaxf(m, __shfl_xor(m, 4));
    float den = 0.f;
    for (unsigned i = lo + l; i < hi; i += 8) {
        float v = ss[src[csr[i]]] + sdn;
        v = v > 0.f ? v : 0.2f * v;
        den += expf(v - m);
    }
    den += __shfl_xor(den, 1);
    den += __shfl_xor(den, 2);
    den += __shfl_xor(den, 4);
    float inv = 1.f / den;
    for (unsigned i = lo + l; i < hi; i += 8) {
        unsigned j = csr[i];
        float v = ss[src[j]] + sdn;
        v = v > 0.f ? v : 0.2f * v;
        alpha[j] = expf(v - m) * inv;
    }
}

// ---------------- aggregation + ELU: wave per node, 2-edge pipelined gathers ------
__global__ void k_agg(const u16* __restrict__ xin, const float* __restrict__ alpha,
                      const unsigned* __restrict__ csr, const unsigned* __restrict__ off,
                      const int* __restrict__ src, u16* __restrict__ outb, int nvalid) {
    int w = threadIdx.x >> 6, l = threadIdx.x & 63;
    int n = blockIdx.x * 4 + w;
    float acc[8] = {};
    if (n < nvalid) {
        unsigned lo = off[n], hi = off[n + 1];
        unsigned i = lo;
        for (; i + 2 <= hi; i += 2) {
            unsigned j0 = csr[i], j1 = csr[i + 1];
            float a0 = alpha[j0], a1 = alpha[j1];
            int s0 = src[j0], s1 = src[j1];
            u16x8 r0 = *(const u16x8*)&xin[(size_t)s0 * 512 + l * 8];
            u16x8 r1 = *(const u16x8*)&xin[(size_t)s1 * 512 + l * 8];
#pragma unroll
            for (int k = 0; k < 8; ++k) acc[k] += a0 * bf2f(r0[k]) + a1 * bf2f(r1[k]);
        }
        if (i < hi) {
            unsigned j0 = csr[i];
            float a0 = alpha[j0];
            int s0 = src[j0];
            u16x8 r0 = *(const u16x8*)&xin[(size_t)s0 * 512 + l * 8];
#pragma unroll
            for (int k = 0; k < 8; ++k) acc[k] += a0 * bf2f(r0[k]);
        }
    }
    u16x8 o;
#pragma unroll
    for (int k = 0; k < 8; ++k) {
        float a = acc[k] > 0.f ? acc[k] : expf(acc[k]) - 1.f;
        o[k] = f2bf(a);
    }
    *(u16x8*)&outb[(size_t)n * 512 + l * 8] = o;
}

// ---------------- aggG: g[n,:] = sum alpha_e * h2[src_e,:]  (30-wide fp32) -------
__global__ void k_aggG(const float* __restrict__ h2, const float* __restrict__ alpha,
                       const unsigned* __restrict__ csr, const unsigned* __restrict__ off,
                       const int* __restrict__ src, float* __restrict__ g) {
    int t = threadIdx.x, grp = t >> 3, l = t & 7;
    int n = blockIdx.x * 32 + grp;
    if (n >= 30000) return;
    unsigned lo = off[n], hi = off[n + 1];
    float acc[4] = {};
    int c0 = l * 4;
    for (unsigned i = lo; i < hi; ++i) {
        unsigned j = csr[i];
        float a = alpha[j];
        const float* row = h2 + (size_t)src[j] * 30;
#pragma unroll
        for (int k = 0; k < 4; ++k) {
            int c = c0 + k;
            if (c < 30) acc[k] += a * row[c];
        }
    }
#pragma unroll
    for (int k = 0; k < 4; ++k) {
        int c = c0 + k;
        if (c < 30) g[(size_t)n * 30 + c] = acc[k];
    }
}

// ---------------- h3[n,:] = elu(g[n,:] @ W2s)  -> bf16 [30080][512] -------------
__global__ void k_h3(const float* __restrict__ g, const float* __restrict__ W2s,
                     u16* __restrict__ h3b) {
    int t = threadIdx.x;
    size_t n0 = (size_t)blockIdx.x * 8;
    float w0[30], w1[30];
#pragma unroll
    for (int o = 0; o < 30; ++o) {
        w0[o] = W2s[(size_t)o * 512 + t];
        w1[o] = W2s[(size_t)o * 512 + t + 256];
    }
    for (int rr = 0; rr < 8; ++rr) {
        size_t n = n0 + rr;
        float a0 = 0.f, a1 = 0.f;
        if (n < 30000) {
            const float* gr = g + n * 30;
#pragma unroll
            for (int o = 0; o < 30; ++o) {
                float v = gr[o];
                a0 += v * w0[o];
                a1 += v * w1[o];
            }
            a0 = a0 > 0.f ? a0 : expf(a0) - 1.f;
            a1 = a1 > 0.f ? a1 : expf(a1) - 1.f;
        }
        h3b[n * 512 + t] = f2bf(a0);
        h3b[n * 512 + t + 256] = f2bf(a1);
    }
}

extern "C" void kernel_launch(void* const* d_in, const int* in_sizes, int n_in,
                              void* d_out, int out_size, void* d_ws, size_t ws_size,
                              hipStream_t stream) {
    const float* X   = (const float*)d_in[0];
    const int*   ei  = (const int*)d_in[1];
    const float* W1s = (const float*)d_in[2];
    const float* W1d = (const float*)d_in[3];
    const float* a1s = (const float*)d_in[4];
    const float* a1d = (const float*)d_in[5];
    const float* W2s = (const float*)d_in[6];
    const int* src = ei;
    const int* dst = ei + 180000;

    float* out = (float*)d_out;
    float* h2 = out;               // [30000][30]
    float* h4 = out + 900000;      // [30000][3000]

    // scratch inside d_out h4 region (dead before gemm5 overwrites it)
    char* ob = (char*)(out + 900000);
    u16* xs1b = (u16*)ob;                                  // 30080*512
    u16* h1b  = (u16*)(ob + 30801920);                     // 30080*512
    float* g  = (float*)(ob + 30801920 + 30801920);        // 30000*30 fp32

    // ws scratch (must survive gemm5): h3b + W1sT + small vectors
    char* w = (char*)d_ws;
    auto carve = [&](size_t bytes) { char* p = w; w += (bytes + 255) & ~(size_t)255; return p; };
    u16* w1sb  = (u16*)carve((size_t)512 * 3008 * 2);
    u16* w1st  = (u16*)carve((size_t)3072 * 512 * 2);
    u16* w2sb  = (u16*)carve((size_t)128 * 512 * 2);
    u16* h3b   = (u16*)carve((size_t)30080 * 512 * 2);
    float* vd    = (float*)carve(3008 * 4);
    float* vs    = (float*)carve(3008 * 4);
    float* ss    = (float*)carve(30000 * 4);
    float* sd    = (float*)carve(30000 * 4);
    float* alpha = (float*)carve(180000 * 4);
    unsigned* deg = (unsigned*)carve(30000 * 4);
    unsigned* off = (unsigned*)carve(30004 * 4);
    unsigned* cur = (unsigned*)carve(30000 * 4);
    unsigned* csr = (unsigned*)carve(180000 * 4);
    unsigned* bsum = (unsigned*)carve(128 * 4);

    hipMemsetAsync(deg, 0, 30000 * 4, stream);

    // merged prep: vd/vs | w1sb | w1st | w2sb | deg
    k_prep<<<2860, 256, 0, stream>>>(W1d, a1d, W1s, a1s, W2s, dst,
                                     vd, vs, w1sb, w1st, w2sb, deg);

    // fused: xs1 = bf16(X) @ W1s^T  +  sd/ss  (replaces convX + gemm1)
    gemm_xw2<<<dim3(4, 235), 256, 0, stream>>>(X, w1sb, xs1b, vd, vs, sd, ss);

    k_scan1<<<118, 256, 0, stream>>>(deg, bsum, 30000);
    k_scanB<<<118, 256, 0, stream>>>(deg, bsum, off, cur, 30000, 118);
    k_fill<<<704, 256, 0, stream>>>(dst, cur, csr);
    k_soft<<<938, 256, 0, stream>>>(src, ss, sd, alpha, csr, off);

    k_agg <<<7520, 256, 0, stream>>>(xs1b, alpha, csr, off, src, h1b, 30000);

    // h2 = h1 @ W2s.T via MFMA
    gemm_bt<false, true><<<dim3(1, 235), 256, 0, stream>>>(h1b, w2sb, h2, 512, 30, 30000, 30);

    // g = agg(alpha, h2);  h3 = elu(g @ W2s)   [agg commutes with linear map]
    k_aggG<<<938, 256, 0, stream>>>(h2, alpha, csr, off, src, g);
    k_h3 <<<3760, 256, 0, stream>>>(g, W2s, h3b);

    gemm_bt<false, true><<<dim3(24, 235), 256, 0, stream>>>(h3b, w1st, h4, 512, 3000, 30000, 3000);
}